// Round 8
// baseline (286.153 us; speedup 1.0000x reference)
//
#include <hip/hip_runtime.h>

// snnTorch Leaky recurrence, reset='subtract':
//   mem_t = 0.95*mem_{t-1} + x_t - spk_{t-1};  spk_t = (mem_t > 1)
// N=8192 independent chains, T=4000 sequential.
//
// Cost model (validated R1/R7): scan time = VALU issue (~56K cyc/wave) +
// ~2.3 cyc per 16B lane-request in the CU's TA/L1 pipe. Requests are fixed
// by layout (N*T*4B / 16B); the TA is PER-CU. R7 used only 128 CUs.
// R8: 16 neurons/wave x 512 blocks = 2 waves/CU on all 256 CUs -> per-CU
// TA work halves (64K->32K requests ~= 74K cyc). Ring structure unchanged:
// 16-deep float4 register ring, slot j refilled at phase j and consumed one
// half later (64-step ~900 cyc flight covers latency). Spikes nibble-packed
// to ws (stores negligible); massively-parallel expand kernel writes the
// 131 MB float output coalesced.
//
// Numerics: exact reference rounding ((0.95*mem + x) - r) via __f*_rn, no
// fma contraction — verified absmax 0.0 in R1-R7. Pack layout identical to
// R4-R7 (word = g>>3, nibble = (g&7)*4).

namespace {

constexpr int T_LEN = 4000;
constexpr int N_NEU = 8192;
constexpr int RPW   = 16;    // neurons per wave (lanes 16-63 fully idle)
constexpr int QROW  = 128;   // packed row stride in u32 (125 used)
constexpr size_t QBYTES = (size_t)N_NEU * QROW * 4;  // 4 MiB ws (fits, R4-R7)

__device__ __forceinline__ unsigned step1(float x, float& mem, float& r) {
    float t = __fmul_rn(0.95f, mem);
    t       = __fadd_rn(t, x);
    mem     = __fsub_rn(t, r);
    bool s  = mem > 1.0f;
    r = s ? 1.0f : 0.0f;      // spike_t == reset_{t+1}
    return s ? 1u : 0u;
}

// Consume ring slots 0..15 (64 steps); refill slot j with group g0+16+j for
// j < PF. Refill issued at phase j, consumed at phase j of the NEXT half ->
// every load gets ~64 steps of flight. sched_barrier pins refills per half.
template <int PF>
__device__ __forceinline__ void half16(const float* __restrict__ p,
                                       float4* __restrict__ ring,
                                       float& mem, float& r,
                                       unsigned& u0, unsigned& u1) {
    u0 = 0; u1 = 0;
#pragma unroll
    for (int j = 0; j < 16; ++j) {
        float4 v = ring[j];
        if (j < PF)
            ring[j] = *reinterpret_cast<const float4*>(p + 64 + 4 * j);
        unsigned b;
        b  = step1(v.x, mem, r);
        b |= step1(v.y, mem, r) << 1;
        b |= step1(v.z, mem, r) << 2;
        b |= step1(v.w, mem, r) << 3;
        const unsigned sh = (j & 7) * 4;
        if (j < 8) u0 |= b << sh; else u1 |= b << sh;
    }
    __builtin_amdgcn_sched_barrier(0);
}

__global__ __launch_bounds__(64, 1)
void snn_scan(const float* __restrict__ x, unsigned* __restrict__ q) {
    const int l = threadIdx.x;
    if (l >= RPW) return;   // wave runs with 16 active lanes; idle lanes add
                            // no TA requests and no VALU beyond the 2cyc/instr
    const size_t n = (size_t)blockIdx.x * RPW + l;  // this lane's neuron
    const float* p = x + n * T_LEN;                 // row base (16B-aligned)
    unsigned* qn = q + n * QROW;

    float mem = 0.0f;   // mem_0 = 0
    float r   = 0.0f;   // reset_1 = H(0-1) = 0

    float4 ring[16];    // static indices -> registers
#pragma unroll
    for (int j = 0; j < 16; ++j)
        ring[j] = *reinterpret_cast<const float4*>(p + 4 * j);

    unsigned w0, w1, w2, w3;
    // Main: 30 pairs x 32 groups = groups 0..959 (words 0..119).
#pragma unroll 1
    for (int k = 0; k < 30; ++k) {
        half16<16>(p,      ring, mem, r, w0, w1);
        half16<16>(p + 64, ring, mem, r, w2, w3);
        *reinterpret_cast<uint4*>(qn) = make_uint4(w0, w1, w2, w3);
        qn += 4;
        p  += 128;
    }
    // Epilogue: groups 960..975 (pf 976..991), 976..991 (pf 992..999).
    half16<16>(p,      ring, mem, r, w0, w1);
    half16<8 >(p + 64, ring, mem, r, w2, w3);
    *reinterpret_cast<uint4*>(qn) = make_uint4(w0, w1, w2, w3);  // words 120..123
    // Final 8 groups (992..999) from ring[0..7] -> word 124.
    unsigned u = 0;
#pragma unroll
    for (int j = 0; j < 8; ++j) {
        float4 v = ring[j];
        unsigned b;
        b  = step1(v.x, mem, r);
        b |= step1(v.y, mem, r) << 1;
        b |= step1(v.z, mem, r) << 2;
        b |= step1(v.w, mem, r) << 3;
        u |= b << (j * 4);
    }
    qn[4] = u;
}

// Expand packed nibbles -> float spikes, fully coalesced float4 writes.
// 8192*1000 float4s = 32000 blocks x 256 threads exactly.
__global__ __launch_bounds__(256)
void snn_expand(const unsigned* __restrict__ q, float* __restrict__ out) {
    const unsigned i = blockIdx.x * 256 + threadIdx.x;  // float4 index
    const unsigned n = i / 1000u;                       // neuron row
    const unsigned c = i - n * 1000u;                   // float4 col
    const unsigned w = q[n * QROW + (c >> 3)];
    const unsigned nib = w >> ((c & 7u) * 4u);
    float4 f;
    f.x = (nib & 1u) ? 1.0f : 0.0f;
    f.y = (nib & 2u) ? 1.0f : 0.0f;
    f.z = (nib & 4u) ? 1.0f : 0.0f;
    f.w = (nib & 8u) ? 1.0f : 0.0f;
    reinterpret_cast<float4*>(out)[i] = f;
}

} // namespace

extern "C" void kernel_launch(void* const* d_in, const int* in_sizes, int n_in,
                              void* d_out, int out_size, void* d_ws, size_t ws_size,
                              hipStream_t stream) {
    const float* x = (const float*)d_in[0];
    float* out     = (float*)d_out;
    unsigned* q    = (unsigned*)d_ws;   // >= 4 MiB (verified R4-R7)
    // 512 blocks x 1 wave, 16 neurons each: 2 waves/CU on all 256 CUs.
    snn_scan<<<dim3(N_NEU / RPW), dim3(64), 0, stream>>>(x, q);
    snn_expand<<<dim3(32000), dim3(256), 0, stream>>>(q, out);
}